// Round 3
// baseline (118.588 us; speedup 1.0000x reference)
//
#include <hip/hip_runtime.h>

// Problem constants (B=4, N=M=8192, D=3)
#define NPTS    8192
#define BATCH   4
#define BLOCK   256
#define S       8                   // queries per thread (registers)
#define QC      (BLOCK * S)         // 2048 queries per block
#define NCHUNK  (NPTS / QC)         // 4
#define MCPB    256                 // DB points per block
#define MCHUNKP (NPTS / MCPB)       // 32
#define NQTOT   (BATCH * 2 * NPTS)  // 65536 queries (both directions)
// grid = BATCH * 2 * NCHUNK * MCHUNKP = 1024 blocks

// ---- Pre-pass: pack both clouds as float4 {x, y, z, |p|^2} ----
// P layout: [cloud(2)][b(4)][NPTS] ; cloud 0 = src, 1 = tgt
__global__ __launch_bounds__(256) void chamfer_prepack(
    const float* __restrict__ src, const float* __restrict__ tgt,
    float4* __restrict__ P)
{
    int idx   = blockIdx.x * 256 + threadIdx.x;  // 0 .. 65535
    int cloud = idx >> 15;                       // 32768 points per cloud
    int r     = idx & 32767;                     // b*NPTS + j
    const float* p = (cloud ? tgt : src) + (size_t)r * 3;
    float x = p[0], y = p[1], z = p[2];
    P[idx] = make_float4(x, y, z, x * x + y * y + z * z);
}

// ---- Main: DB points broadcast via SGPRs (scalar loads), no LDS ----
// bid bits: [4:0]=mc, [6:5]=nc, [7]=dir, [9:8]=b
__global__ __launch_bounds__(BLOCK) void chamfer_main(
    const float4* __restrict__ P,
    float* __restrict__ minarr)     // [MCHUNKP][NQTOT] partial mins
{
    const int bid = blockIdx.x;
    const int mc  = bid & (MCHUNKP - 1);
    const int nc  = (bid >> 5) & (NCHUNK - 1);
    const int dir = (bid >> 7) & 1;
    const int b   = bid >> 8;
    const int tid = threadIdx.x;

    // dir 0: queries from src (cloud 0), DB from tgt (cloud 1); dir 1 swapped.
    const float4* Qp = P + ((size_t)dir * BATCH + b) * NPTS;
    const float4* Tp = P + ((size_t)(1 - dir) * BATCH + b) * NPTS + mc * MCPB;

    // Per-lane query registers, pre-scaled by -2; hq = |q|^2 from .w
    const int n0 = nc * QC;
    float qx[S], qy[S], qz[S], hq[S], mn[S];
    #pragma unroll
    for (int s = 0; s < S; ++s) {
        float4 a = Qp[n0 + tid + s * BLOCK];
        qx[s] = -2.0f * a.x;
        qy[s] = -2.0f * a.y;
        qz[s] = -2.0f * a.z;
        hq[s] = a.w;
        mn[s] = 3.0e38f;
    }

    // Inner loop: 4 wave-uniform DB points per iter -> s_load_dwordx16,
    // coords consumed as SGPR operands of v_fma_f32 (1 SGPR/instr budget).
    #pragma unroll 2
    for (int g = 0; g < MCPB / 4; ++g) {
        float4 a0 = Tp[4 * g + 0];
        float4 a1 = Tp[4 * g + 1];
        float4 a2 = Tp[4 * g + 2];
        float4 a3 = Tp[4 * g + 3];
        #pragma unroll
        for (int s = 0; s < S; ++s) {
            // d = |t|^2 - 2 q.t  (|q|^2 added after the min)
            float d0 = fmaf(qx[s], a0.x, fmaf(qy[s], a0.y, fmaf(qz[s], a0.z, a0.w)));
            float d1 = fmaf(qx[s], a1.x, fmaf(qy[s], a1.y, fmaf(qz[s], a1.z, a1.w)));
            float d2 = fmaf(qx[s], a2.x, fmaf(qy[s], a2.y, fmaf(qz[s], a2.z, a2.w)));
            float d3 = fmaf(qx[s], a3.x, fmaf(qy[s], a3.y, fmaf(qz[s], a3.z, a3.w)));
            mn[s] = fminf(fminf(mn[s], d0), d1);   // v_min3_f32
            mn[s] = fminf(fminf(mn[s], d2), d3);   // v_min3_f32
        }
    }

    // Store partial mins (every cell written exactly once; no ws memset)
    float* base = minarr + (size_t)mc * NQTOT + ((size_t)(b * 2 + dir)) * NPTS + n0 + tid;
    #pragma unroll
    for (int s = 0; s < S; ++s) {
        base[s * BLOCK] = mn[s] + hq[s];
    }
}

// ---- Reduce: 256 blocks x 256 threads, one query each ----
__global__ __launch_bounds__(256) void chamfer_reduce(
    const float* __restrict__ minarr, float* __restrict__ out)
{
    const int q = blockIdx.x * 256 + threadIdx.x;
    float m = 3.4e38f;
    #pragma unroll
    for (int mc = 0; mc < MCHUNKP; ++mc)
        m = fminf(m, minarr[(size_t)mc * NQTOT + q]);

    float acc = m;
    #pragma unroll
    for (int off = 32; off > 0; off >>= 1) acc += __shfl_down(acc, off);

    __shared__ float sdata[4];
    if ((threadIdx.x & 63) == 0) sdata[threadIdx.x >> 6] = acc;
    __syncthreads();
    if (threadIdx.x == 0) {
        float t = (sdata[0] + sdata[1]) + (sdata[2] + sdata[3]);
        atomicAdd(out, t * (1.0f / (float)(BATCH * NPTS)));
    }
}

extern "C" void kernel_launch(void* const* d_in, const int* in_sizes, int n_in,
                              void* d_out, int out_size, void* d_ws, size_t ws_size,
                              hipStream_t stream) {
    const float* src = (const float*)d_in[0];   // (B, N, 3) fp32
    const float* tgt = (const float*)d_in[1];   // (B, M, 3) fp32
    float* out = (float*)d_out;                 // scalar fp32

    float*  minarr = (float*)d_ws;                                   // 8 MB
    float4* P      = (float4*)((char*)d_ws + (size_t)MCHUNKP * NQTOT * sizeof(float)); // 1 MB

    hipMemsetAsync(out, 0, sizeof(float), stream);  // d_out poisoned 0xAA
    chamfer_prepack<<<NQTOT / 256, 256, 0, stream>>>(src, tgt, P);
    chamfer_main<<<BATCH * 2 * NCHUNK * MCHUNKP, BLOCK, 0, stream>>>(P, minarr);
    chamfer_reduce<<<NQTOT / 256, 256, 0, stream>>>(minarr, out);
}

// Round 4
// 100.814 us; speedup vs baseline: 1.1763x; 1.1763x over previous
//
#include <hip/hip_runtime.h>

// Problem constants (B=4, N=M=8192, D=3)
#define NPTS   8192
#define BATCH  4
#define BLOCK  256
#define S      16                 // queries per thread (registers)
#define QC     (BLOCK * S)        // 4096 queries per block
#define NCHUNK (NPTS / QC)        // 2
#define MC     256                // DB points per block (LDS chunk)
#define MCHUNK (NPTS / MC)        // 32
#define NQTOT  (BATCH * 2 * NPTS) // 65536 queries (both directions)
// grid = BATCH * 2 * NCHUNK * MCHUNK = 512 blocks

// Sign-aware float atomic min (cells init to 0x7F7F7F7F = 3.39e38f).
__device__ __forceinline__ void atomic_min_float(float* addr, float val) {
    if (val >= 0.0f) {
        atomicMin((int*)addr, __float_as_int(val));
    } else {
        atomicMax((unsigned int*)addr, __float_as_uint(val));
    }
}

// bid bits: [4:0]=mc, [5]=nc, [6]=dir, [8:7]=b
__global__ __launch_bounds__(BLOCK) void chamfer_main(
    const float* __restrict__ src,
    const float* __restrict__ tgt,
    float* __restrict__ minarr)   // [NQTOT] running mins (atomic)
{
    __shared__ float4 Xs4[MC / 4], Ys4[MC / 4], Zs4[MC / 4], Hs4[MC / 4];
    float* Xs = (float*)Xs4;
    float* Ys = (float*)Ys4;
    float* Zs = (float*)Zs4;
    float* Hs = (float*)Hs4;

    const int bid = blockIdx.x;
    const int mc  = bid & (MCHUNK - 1);
    const int nc  = (bid >> 5) & (NCHUNK - 1);
    const int dir = (bid >> 6) & 1;
    const int b   = bid >> 7;
    const int tid = threadIdx.x;

    const float* Q = dir ? tgt : src;   // dir 0: fwd (src->tgt); dir 1: bwd
    const float* T = dir ? src : tgt;

    // ---- Stage DB chunk (MC == BLOCK: one point per thread) ----
    const int m0 = mc * MC;
    {
        const float* p = T + ((size_t)b * NPTS + m0 + tid) * 3;
        float x = p[0], y = p[1], z = p[2];
        Xs[tid] = x; Ys[tid] = y; Zs[tid] = z;
        Hs[tid] = x * x + y * y + z * z;
    }

    // ---- Load S=16 query points; pre-scale by -2 ----
    const int n0 = nc * QC;
    float qx[S], qy[S], qz[S], hq[S], mn[S];
    #pragma unroll
    for (int s = 0; s < S; ++s) {
        int n = n0 + tid + s * BLOCK;
        const float* p = Q + ((size_t)b * NPTS + n) * 3;
        float x = p[0], y = p[1], z = p[2];
        qx[s] = -2.0f * x;
        qy[s] = -2.0f * y;
        qz[s] = -2.0f * z;
        hq[s] = x * x + y * y + z * z;
        mn[s] = 3.0e38f;
    }
    __syncthreads();

    // ---- Inner loop: 4 DB points / iter, broadcast LDS reads ----
    // Per group: 4 ds_read_b128 amortized over 64 pairs (S=16).
    for (int jq = 0; jq < MC / 4; ++jq) {
        float4 x4 = Xs4[jq], y4 = Ys4[jq], z4 = Zs4[jq], h4 = Hs4[jq];
        #pragma unroll
        for (int s = 0; s < S; ++s) {
            float d0 = fmaf(qx[s], x4.x, fmaf(qy[s], y4.x, fmaf(qz[s], z4.x, h4.x)));
            float d1 = fmaf(qx[s], x4.y, fmaf(qy[s], y4.y, fmaf(qz[s], z4.y, h4.y)));
            float d2 = fmaf(qx[s], x4.z, fmaf(qy[s], y4.z, fmaf(qz[s], z4.z, h4.z)));
            float d3 = fmaf(qx[s], x4.w, fmaf(qy[s], y4.w, fmaf(qz[s], z4.w, h4.w)));
            mn[s] = fminf(fminf(mn[s], d0), d1);   // v_min3_f32
            mn[s] = fminf(fminf(mn[s], d2), d3);   // v_min3_f32
        }
    }

    // ---- Atomic-min combine across m-chunks (256 KB array) ----
    float* base = minarr + ((size_t)(b * 2 + dir)) * NPTS + n0 + tid;
    #pragma unroll
    for (int s = 0; s < S; ++s) {
        atomic_min_float(base + s * BLOCK, mn[s] + hq[s]);
    }
}

// ---- Reduce: 256 blocks x 256 threads, one query each (256 KB total) ----
__global__ __launch_bounds__(256) void chamfer_reduce(
    const float* __restrict__ minarr, float* __restrict__ out)
{
    const int q = blockIdx.x * 256 + threadIdx.x;
    float acc = minarr[q];
    #pragma unroll
    for (int off = 32; off > 0; off >>= 1) acc += __shfl_down(acc, off);

    __shared__ float sdata[4];
    if ((threadIdx.x & 63) == 0) sdata[threadIdx.x >> 6] = acc;
    __syncthreads();
    if (threadIdx.x == 0) {
        float t = (sdata[0] + sdata[1]) + (sdata[2] + sdata[3]);
        atomicAdd(out, t * (1.0f / (float)(BATCH * NPTS)));
    }
}

extern "C" void kernel_launch(void* const* d_in, const int* in_sizes, int n_in,
                              void* d_out, int out_size, void* d_ws, size_t ws_size,
                              hipStream_t stream) {
    const float* src = (const float*)d_in[0];   // (B, N, 3) fp32
    const float* tgt = (const float*)d_in[1];   // (B, M, 3) fp32
    float* minarr = (float*)d_ws;               // [NQTOT] = 256 KB
    float* out = (float*)d_out;                 // scalar fp32

    hipMemsetAsync(minarr, 0x7F, (size_t)NQTOT * sizeof(float), stream); // 3.39e38f
    hipMemsetAsync(out, 0, sizeof(float), stream);                       // 0xAA poisoned
    chamfer_main<<<BATCH * 2 * NCHUNK * MCHUNK, BLOCK, 0, stream>>>(src, tgt, minarr);
    chamfer_reduce<<<NQTOT / 256, 256, 0, stream>>>(minarr, out);
}

// Round 5
// 94.627 us; speedup vs baseline: 1.2532x; 1.0654x over previous
//
#include <hip/hip_runtime.h>

// Problem constants (B=4, N=M=8192, D=3)
#define NPTS   8192
#define BATCH  4
#define MSPLIT 4                 // m-range splits per (b,dir)
#define QB     4                 // query tiles (32 queries each) per wave
#define MB     2                 // db tiles per inner iteration
#define TILES  (NPTS / 32)       // 256 point-tiles per (cloud,b)
#define TPB    (TILES / MSPLIT)  // 64 db tiles per block
#define NQTOT  (BATCH * 2 * NPTS)

typedef _Float16 f16x8  __attribute__((ext_vector_type(8)));
typedef float    f32x16 __attribute__((ext_vector_type(16)));

// ws layout (bytes):
//   TA  [8 bd][256 tile][64 lane] f16x8   @ 0        (2 MB)  db-role frags
//   QF  [8 bd][256 tile][64 lane] f16x8   @ 2 MB     (2 MB)  query-role frags
//   H   [8 bd][8192] fp32                 @ 4 MB     (256 KB) |p|^2 exact
//   MIN [MSPLIT][8 bd][8192] fp32         @ 4.25 MB  (1 MB)  partial mins
#define TA_OFF  0
#define QF_OFF  (2u << 20)
#define H_OFF   (4u << 20)
#define MIN_OFF ((4u << 20) + (256u << 10))

// ---- Prepack: per point build hi/lo f16 split K-vectors in MFMA lane order.
// A (db role)   k = [th.x th.y th.z  th.x th.y th.z  tl.x tl.y | tl.z tl.x tl.y tl.z  hth htl 0 0]
// B (query role)k = [rh.x rh.y rh.z  rl.x rl.y rl.z  rh.x rh.y | rh.z rl.x rl.y rl.z  1   1   0 0]
// (r = -2q). Dot = rh·th + rl·th + rh·tl + rl·tl + hth + htl ≈ ht - 2 q·t.
__global__ __launch_bounds__(256) void chamfer_prepack(
    const float* __restrict__ src, const float* __restrict__ tgt,
    f16x8* __restrict__ TA, f16x8* __restrict__ QF, float* __restrict__ H)
{
    int tid = blockIdx.x * 256 + threadIdx.x;      // (c*4+b)*8192 + pt
    int c   = tid >> 15;
    int r   = tid & 32767;                         // b*8192 + pt
    const float* p = (c ? tgt : src) + (size_t)r * 3;
    float x = p[0], y = p[1], z = p[2];
    float h = x * x + y * y + z * z;
    H[tid] = h;

    _Float16 thx = (_Float16)x, thy = (_Float16)y, thz = (_Float16)z;
    _Float16 tlx = (_Float16)(x - (float)thx);
    _Float16 tly = (_Float16)(y - (float)thy);
    _Float16 tlz = (_Float16)(z - (float)thz);
    _Float16 hh  = (_Float16)h;
    _Float16 hl  = (_Float16)(h - (float)hh);

    float rx = -2.f * x, ry = -2.f * y, rz = -2.f * z;
    _Float16 rhx = (_Float16)rx, rhy = (_Float16)ry, rhz = (_Float16)rz;
    _Float16 rlx = (_Float16)(rx - (float)rhx);
    _Float16 rly = (_Float16)(ry - (float)rhy);
    _Float16 rlz = (_Float16)(rz - (float)rhz);

    int pt   = r & 8191;
    int bd   = tid >> 13;                          // c*4+b
    int tile = pt >> 5, ln = pt & 31;
    size_t base = ((size_t)bd * TILES + tile) * 64;

    _Float16 z0 = (_Float16)0.f, one = (_Float16)1.f;
    f16x8 alo = {thx, thy, thz, thx, thy, thz, tlx, tly};
    f16x8 ahi = {tlz, tlx, tly, tlz, hh,  hl,  z0,  z0 };
    TA[base + ln]      = alo;
    TA[base + 32 + ln] = ahi;
    f16x8 blo = {rhx, rhy, rhz, rlx, rly, rlz, rhx, rhy};
    f16x8 bhi = {rhz, rlx, rly, rlz, one, one, z0,  z0 };
    QF[base + ln]      = blo;
    QF[base + 32 + ln] = bhi;
}

// min3 tree over the 16 C regs (rows = 16 of 32 db points; other half in lane^32)
__device__ __forceinline__ float red16(const f32x16& d) {
    float a = fminf(fminf(d[0],  d[1]),  d[2]);
    float b = fminf(fminf(d[3],  d[4]),  d[5]);
    float c = fminf(fminf(d[6],  d[7]),  d[8]);
    float e = fminf(fminf(d[9],  d[10]), d[11]);
    float f = fminf(fminf(d[12], d[13]), d[14]);
    float g = fminf(fminf(a, b), d[15]);
    float h = fminf(fminf(c, e), f);
    return fminf(g, h);
}

// ---- Main: one wave per block (64 thr). grid = 64(qw) * 8(bd) * MSPLIT = 2048.
// Wave holds QB=4 query fragments (128 queries) fixed; streams db fragments.
__global__ __launch_bounds__(64) void chamfer_main(
    const f16x8* __restrict__ TA, const f16x8* __restrict__ QF,
    float* __restrict__ minarr)
{
    const int bid  = blockIdx.x;
    const int qw   = bid & 63;
    const int bd   = (bid >> 6) & 7;     // dir*4+b (queries from cloud=dir)
    const int ms   = bid >> 9;
    const int lane = threadIdx.x;
    const int bdT  = bd ^ 4;             // db side = opposite cloud

    f16x8 qf[QB];
    size_t qbase = ((size_t)bd * TILES + qw * QB) * 64 + lane;
    #pragma unroll
    for (int t = 0; t < QB; ++t) qf[t] = QF[qbase + t * 64];

    const f32x16 zero = {0.f,0.f,0.f,0.f,0.f,0.f,0.f,0.f,
                         0.f,0.f,0.f,0.f,0.f,0.f,0.f,0.f};
    float mn[QB];
    #pragma unroll
    for (int t = 0; t < QB; ++t) mn[t] = 3.0e38f;

    size_t tbase = ((size_t)bdT * TILES + ms * TPB) * 64 + lane;
    for (int i = 0; i < TPB / MB; ++i) {
        f16x8 a0 = TA[tbase + (size_t)(2 * i)     * 64];
        f16x8 a1 = TA[tbase + (size_t)(2 * i + 1) * 64];
        #pragma unroll
        for (int t = 0; t < QB; ++t) {
            f32x16 d0 = __builtin_amdgcn_mfma_f32_32x32x16_f16(a0, qf[t], zero, 0, 0, 0);
            f32x16 d1 = __builtin_amdgcn_mfma_f32_32x32x16_f16(a1, qf[t], zero, 0, 0, 0);
            mn[t] = fminf(mn[t], fminf(red16(d0), red16(d1)));
        }
    }

    // Each lane covered 16 of 32 rows per tile; other 16 rows are in lane^32.
    #pragma unroll
    for (int t = 0; t < QB; ++t) mn[t] = fminf(mn[t], __shfl_xor(mn[t], 32));

    if (lane < 32) {
        float* base = minarr + (size_t)ms * NQTOT + (size_t)bd * NPTS + qw * (QB * 32) + lane;
        #pragma unroll
        for (int t = 0; t < QB; ++t) base[t * 32] = mn[t];
    }
}

// ---- Reduce: min over MSPLIT partials, + |q|^2, sum, scale ----
__global__ __launch_bounds__(256) void chamfer_reduce(
    const float* __restrict__ minarr, const float* __restrict__ H,
    float* __restrict__ out)
{
    const int q = blockIdx.x * 256 + threadIdx.x;   // bd*8192 + n
    float m = fminf(fminf(minarr[0 * NQTOT + q], minarr[1 * NQTOT + q]),
                    fminf(minarr[2 * NQTOT + q], minarr[3 * NQTOT + q]));
    float acc = m + H[q];
    #pragma unroll
    for (int off = 32; off > 0; off >>= 1) acc += __shfl_down(acc, off);

    __shared__ float sdata[4];
    if ((threadIdx.x & 63) == 0) sdata[threadIdx.x >> 6] = acc;
    __syncthreads();
    if (threadIdx.x == 0) {
        float t = (sdata[0] + sdata[1]) + (sdata[2] + sdata[3]);
        atomicAdd(out, t * (1.0f / (float)(BATCH * NPTS)));
    }
}

extern "C" void kernel_launch(void* const* d_in, const int* in_sizes, int n_in,
                              void* d_out, int out_size, void* d_ws, size_t ws_size,
                              hipStream_t stream) {
    const float* src = (const float*)d_in[0];   // (B, N, 3) fp32
    const float* tgt = (const float*)d_in[1];   // (B, M, 3) fp32
    float* out = (float*)d_out;

    f16x8* TA     = (f16x8*)((char*)d_ws + TA_OFF);
    f16x8* QF     = (f16x8*)((char*)d_ws + QF_OFF);
    float* H      = (float*)((char*)d_ws + H_OFF);
    float* minarr = (float*)((char*)d_ws + MIN_OFF);

    hipMemsetAsync(out, 0, sizeof(float), stream);  // d_out poisoned 0xAA
    chamfer_prepack<<<NQTOT / 256, 256, 0, stream>>>(src, tgt, TA, QF, H);
    chamfer_main<<<64 * 8 * MSPLIT, 64, 0, stream>>>(TA, QF, minarr);
    chamfer_reduce<<<NQTOT / 256, 256, 0, stream>>>(minarr, H, out);
}

// Round 6
// 87.899 us; speedup vs baseline: 1.3491x; 1.0765x over previous
//
#include <hip/hip_runtime.h>

// Problem constants (B=4, N=M=8192, D=3)
#define NPTS   8192
#define BATCH  4
#define MSPLIT 8                 // m-range splits per (b,dir)
#define QB     4                 // query tiles (32 queries each) per wave
#define MB     2                 // db tiles per inner iteration
#define TILES  (NPTS / 32)       // 256 point-tiles per (cloud,b)
#define TPB    (TILES / MSPLIT)  // 32 db tiles per block
#define ITER   (TPB / MB)        // 16 inner iterations
#define NQTOT  (BATCH * 2 * NPTS)

typedef _Float16 f16x8  __attribute__((ext_vector_type(8)));
typedef float    f32x16 __attribute__((ext_vector_type(16)));

// ws layout (bytes):
//   TA  [8 bd][256 tile][64 lane] f16x8   @ 0        (2 MB)  db-role frags
//   QF  [8 bd][256 tile][64 lane] f16x8   @ 2 MB     (2 MB)  query-role frags
//   H   [8 bd][8192] fp32                 @ 4 MB     (256 KB) |p|^2 exact
//   MIN [MSPLIT][8 bd][8192] fp32         @ 4.25 MB  (2 MB)  partial mins
#define TA_OFF  0
#define QF_OFF  (2u << 20)
#define H_OFF   (4u << 20)
#define MIN_OFF ((4u << 20) + (256u << 10))

// ---- Prepack: per point build hi/lo f16 split K-vectors in MFMA lane order.
// A (db role)   k = [th.x th.y th.z  th.x th.y th.z  tl.x tl.y | tl.z tl.x tl.y tl.z  hth htl 0 0]
// B (query role)k = [rh.x rh.y rh.z  rl.x rl.y rl.z  rh.x rh.y | rh.z rl.x rl.y rl.z  1   1   0 0]
// (r = -2q). Dot = rh·th + rl·th + rh·tl + rl·tl + hth + htl ≈ ht - 2 q·t.
__global__ __launch_bounds__(256) void chamfer_prepack(
    const float* __restrict__ src, const float* __restrict__ tgt,
    f16x8* __restrict__ TA, f16x8* __restrict__ QF, float* __restrict__ H,
    float* __restrict__ out)
{
    int tid = blockIdx.x * 256 + threadIdx.x;      // (c*4+b)*8192 + pt
    if (tid == 0) out[0] = 0.0f;                   // replaces memset dispatch
    int c   = tid >> 15;
    int r   = tid & 32767;                         // b*8192 + pt
    const float* p = (c ? tgt : src) + (size_t)r * 3;
    float x = p[0], y = p[1], z = p[2];
    float h = x * x + y * y + z * z;
    H[tid] = h;

    _Float16 thx = (_Float16)x, thy = (_Float16)y, thz = (_Float16)z;
    _Float16 tlx = (_Float16)(x - (float)thx);
    _Float16 tly = (_Float16)(y - (float)thy);
    _Float16 tlz = (_Float16)(z - (float)thz);
    _Float16 hh  = (_Float16)h;
    _Float16 hl  = (_Float16)(h - (float)hh);

    float rx = -2.f * x, ry = -2.f * y, rz = -2.f * z;
    _Float16 rhx = (_Float16)rx, rhy = (_Float16)ry, rhz = (_Float16)rz;
    _Float16 rlx = (_Float16)(rx - (float)rhx);
    _Float16 rly = (_Float16)(ry - (float)rhy);
    _Float16 rlz = (_Float16)(rz - (float)rhz);

    int pt   = r & 8191;
    int bd   = tid >> 13;                          // c*4+b
    int tile = pt >> 5, ln = pt & 31;
    size_t base = ((size_t)bd * TILES + tile) * 64;

    _Float16 z0 = (_Float16)0.f, one = (_Float16)1.f;
    f16x8 alo = {thx, thy, thz, thx, thy, thz, tlx, tly};
    f16x8 ahi = {tlz, tlx, tly, tlz, hh,  hl,  z0,  z0 };
    TA[base + ln]      = alo;
    TA[base + 32 + ln] = ahi;
    f16x8 blo = {rhx, rhy, rhz, rlx, rly, rlz, rhx, rhy};
    f16x8 bhi = {rhz, rlx, rly, rlz, one, one, z0,  z0 };
    QF[base + ln]      = blo;
    QF[base + 32 + ln] = bhi;
}

// min3 tree over the 16 C regs (rows = 16 of 32 db points; other half in lane^32)
__device__ __forceinline__ float red16(const f32x16& d) {
    float a = fminf(fminf(d[0],  d[1]),  d[2]);
    float b = fminf(fminf(d[3],  d[4]),  d[5]);
    float c = fminf(fminf(d[6],  d[7]),  d[8]);
    float e = fminf(fminf(d[9],  d[10]), d[11]);
    float f = fminf(fminf(d[12], d[13]), d[14]);
    float g = fminf(fminf(a, b), d[15]);
    float h = fminf(fminf(c, e), f);
    return fminf(g, h);
}

// ---- Main: one wave per block. grid = 64(qw) * 8(bd) * MSPLIT = 4096.
// 16 waves/CU (4/SIMD) -> MFMA pipe and VALU min-tree overlap across waves.
__global__ __launch_bounds__(64) void chamfer_main(
    const f16x8* __restrict__ TA, const f16x8* __restrict__ QF,
    float* __restrict__ minarr)
{
    const int bid  = blockIdx.x;
    const int qw   = bid & 63;
    const int bd   = (bid >> 6) & 7;     // dir*4+b (queries from cloud=dir)
    const int ms   = bid >> 9;           // 0..MSPLIT-1
    const int lane = threadIdx.x;
    const int bdT  = bd ^ 4;             // db side = opposite cloud

    f16x8 qf[QB];
    size_t qbase = ((size_t)bd * TILES + qw * QB) * 64 + lane;
    #pragma unroll
    for (int t = 0; t < QB; ++t) qf[t] = QF[qbase + t * 64];

    const f32x16 zero = {0.f,0.f,0.f,0.f,0.f,0.f,0.f,0.f,
                         0.f,0.f,0.f,0.f,0.f,0.f,0.f,0.f};
    float mn[QB];
    #pragma unroll
    for (int t = 0; t < QB; ++t) mn[t] = 3.0e38f;

    const size_t tbase = ((size_t)bdT * TILES + ms * TPB) * 64 + lane;

    // Software-pipelined: prefetch next MB tiles while reducing current.
    f16x8 a0 = TA[tbase];
    f16x8 a1 = TA[tbase + 64];
    for (int i = 0; i < ITER - 1; ++i) {
        f16x8 n0 = TA[tbase + (size_t)(2 * i + 2) * 64];
        f16x8 n1 = TA[tbase + (size_t)(2 * i + 3) * 64];
        #pragma unroll
        for (int t = 0; t < QB; ++t) {
            f32x16 d0 = __builtin_amdgcn_mfma_f32_32x32x16_f16(a0, qf[t], zero, 0, 0, 0);
            f32x16 d1 = __builtin_amdgcn_mfma_f32_32x32x16_f16(a1, qf[t], zero, 0, 0, 0);
            mn[t] = fminf(mn[t], fminf(red16(d0), red16(d1)));
        }
        a0 = n0; a1 = n1;
    }
    #pragma unroll
    for (int t = 0; t < QB; ++t) {
        f32x16 d0 = __builtin_amdgcn_mfma_f32_32x32x16_f16(a0, qf[t], zero, 0, 0, 0);
        f32x16 d1 = __builtin_amdgcn_mfma_f32_32x32x16_f16(a1, qf[t], zero, 0, 0, 0);
        mn[t] = fminf(mn[t], fminf(red16(d0), red16(d1)));
    }

    // Each lane covered 16 of 32 rows per tile; other 16 rows are in lane^32.
    #pragma unroll
    for (int t = 0; t < QB; ++t) mn[t] = fminf(mn[t], __shfl_xor(mn[t], 32));

    if (lane < 32) {
        float* base = minarr + (size_t)ms * NQTOT + (size_t)bd * NPTS + qw * (QB * 32) + lane;
        #pragma unroll
        for (int t = 0; t < QB; ++t) base[t * 32] = mn[t];
    }
}

// ---- Reduce: min over MSPLIT partials, + |q|^2, sum, scale ----
__global__ __launch_bounds__(256) void chamfer_reduce(
    const float* __restrict__ minarr, const float* __restrict__ H,
    float* __restrict__ out)
{
    const int q = blockIdx.x * 256 + threadIdx.x;   // bd*8192 + n
    float m = 3.4e38f;
    #pragma unroll
    for (int ms = 0; ms < MSPLIT; ++ms)
        m = fminf(m, minarr[(size_t)ms * NQTOT + q]);
    float acc = m + H[q];
    #pragma unroll
    for (int off = 32; off > 0; off >>= 1) acc += __shfl_down(acc, off);

    __shared__ float sdata[4];
    if ((threadIdx.x & 63) == 0) sdata[threadIdx.x >> 6] = acc;
    __syncthreads();
    if (threadIdx.x == 0) {
        float t = (sdata[0] + sdata[1]) + (sdata[2] + sdata[3]);
        atomicAdd(out, t * (1.0f / (float)(BATCH * NPTS)));
    }
}

extern "C" void kernel_launch(void* const* d_in, const int* in_sizes, int n_in,
                              void* d_out, int out_size, void* d_ws, size_t ws_size,
                              hipStream_t stream) {
    const float* src = (const float*)d_in[0];   // (B, N, 3) fp32
    const float* tgt = (const float*)d_in[1];   // (B, M, 3) fp32
    float* out = (float*)d_out;

    f16x8* TA     = (f16x8*)((char*)d_ws + TA_OFF);
    f16x8* QF     = (f16x8*)((char*)d_ws + QF_OFF);
    float* H      = (float*)((char*)d_ws + H_OFF);
    float* minarr = (float*)((char*)d_ws + MIN_OFF);

    chamfer_prepack<<<NQTOT / 256, 256, 0, stream>>>(src, tgt, TA, QF, H, out);
    chamfer_main<<<64 * 8 * MSPLIT, 64, 0, stream>>>(TA, QF, minarr);
    chamfer_reduce<<<NQTOT / 256, 256, 0, stream>>>(minarr, H, out);
}

// Round 7
// 85.174 us; speedup vs baseline: 1.3923x; 1.0320x over previous
//
#include <hip/hip_runtime.h>

// Problem constants (B=4, N=M=8192, D=3)
#define NPTS   8192
#define BATCH  4
#define MSPLIT 16                // m-range splits per (b,dir)
#define QB     4                 // query tiles (32 queries each) per wave
#define TILES  (NPTS / 32)       // 256 point-tiles per (cloud,b)
#define TPB    (TILES / MSPLIT)  // 16 db tiles per block
#define ITER   TPB               // MB=1: one tile per inner iteration
#define NQTOT  (BATCH * 2 * NPTS)

typedef _Float16 f16x8  __attribute__((ext_vector_type(8)));
typedef float    f32x16 __attribute__((ext_vector_type(16)));

// ws layout (bytes):
//   TA  [8 bd][256 tile][64 lane] f16x8   @ 0        (2 MB)  db-role frags
//   QF  [8 bd][256 tile][64 lane] f16x8   @ 2 MB     (2 MB)  query-role frags
//   H   [8 bd][8192] fp32                 @ 4 MB     (256 KB) |p|^2 exact
//   MIN [MSPLIT][8 bd][8192] fp32         @ 4.25 MB  (4 MB)  partial mins
#define TA_OFF  0
#define QF_OFF  (2u << 20)
#define H_OFF   (4u << 20)
#define MIN_OFF ((4u << 20) + (256u << 10))

// ---- Prepack: per point build hi/lo f16 split K-vectors in MFMA lane order.
// A (db role)   k = [th.x th.y th.z  th.x th.y th.z  tl.x tl.y | tl.z tl.x tl.y tl.z  hth htl 0 0]
// B (query role)k = [rh.x rh.y rh.z  rl.x rl.y rl.z  rh.x rh.y | rh.z rl.x rl.y rl.z  1   1   0 0]
// (r = -2q). Dot = rh·th + rl·th + rh·tl + rl·tl + hth + htl ≈ ht - 2 q·t.
__global__ __launch_bounds__(256) void chamfer_prepack(
    const float* __restrict__ src, const float* __restrict__ tgt,
    f16x8* __restrict__ TA, f16x8* __restrict__ QF, float* __restrict__ H,
    float* __restrict__ out)
{
    int tid = blockIdx.x * 256 + threadIdx.x;      // (c*4+b)*8192 + pt
    if (tid == 0) out[0] = 0.0f;                   // replaces memset dispatch
    int c   = tid >> 15;
    int r   = tid & 32767;                         // b*8192 + pt
    const float* p = (c ? tgt : src) + (size_t)r * 3;
    float x = p[0], y = p[1], z = p[2];
    float h = x * x + y * y + z * z;
    H[tid] = h;

    _Float16 thx = (_Float16)x, thy = (_Float16)y, thz = (_Float16)z;
    _Float16 tlx = (_Float16)(x - (float)thx);
    _Float16 tly = (_Float16)(y - (float)thy);
    _Float16 tlz = (_Float16)(z - (float)thz);
    _Float16 hh  = (_Float16)h;
    _Float16 hl  = (_Float16)(h - (float)hh);

    float rx = -2.f * x, ry = -2.f * y, rz = -2.f * z;
    _Float16 rhx = (_Float16)rx, rhy = (_Float16)ry, rhz = (_Float16)rz;
    _Float16 rlx = (_Float16)(rx - (float)rhx);
    _Float16 rly = (_Float16)(ry - (float)rhy);
    _Float16 rlz = (_Float16)(rz - (float)rhz);

    int pt   = r & 8191;
    int bd   = tid >> 13;                          // c*4+b
    int tile = pt >> 5, ln = pt & 31;
    size_t base = ((size_t)bd * TILES + tile) * 64;

    _Float16 z0 = (_Float16)0.f, one = (_Float16)1.f;
    f16x8 alo = {thx, thy, thz, thx, thy, thz, tlx, tly};
    f16x8 ahi = {tlz, tlx, tly, tlz, hh,  hl,  z0,  z0 };
    TA[base + ln]      = alo;
    TA[base + 32 + ln] = ahi;
    f16x8 blo = {rhx, rhy, rhz, rlx, rly, rlz, rhx, rhy};
    f16x8 bhi = {rhz, rlx, rly, rlz, one, one, z0,  z0 };
    QF[base + ln]      = blo;
    QF[base + 32 + ln] = bhi;
}

// min3 tree over the 16 C regs (rows = 16 of 32 db points; other half in lane^32)
__device__ __forceinline__ float red16(const f32x16& d) {
    float a = fminf(fminf(d[0],  d[1]),  d[2]);
    float b = fminf(fminf(d[3],  d[4]),  d[5]);
    float c = fminf(fminf(d[6],  d[7]),  d[8]);
    float e = fminf(fminf(d[9],  d[10]), d[11]);
    float f = fminf(fminf(d[12], d[13]), d[14]);
    float g = fminf(fminf(a, b), d[15]);
    float h = fminf(fminf(c, e), f);
    return fminf(g, h);
}

// ---- Main: one wave per block. grid = 64(qw) * 8(bd) * 16(ms) = 8192.
// __launch_bounds__(64,8): force VGPR<=64 -> 8 waves/SIMD residency.
__global__ __launch_bounds__(64, 8) void chamfer_main(
    const f16x8* __restrict__ TA, const f16x8* __restrict__ QF,
    float* __restrict__ minarr)
{
    const int bid  = blockIdx.x;
    const int qw   = bid & 63;
    const int bd   = (bid >> 6) & 7;     // dir*4+b (queries from cloud=dir)
    const int ms   = bid >> 9;           // 0..MSPLIT-1
    const int lane = threadIdx.x;
    const int bdT  = bd ^ 4;             // db side = opposite cloud

    f16x8 qf[QB];
    size_t qbase = ((size_t)bd * TILES + qw * QB) * 64 + lane;
    #pragma unroll
    for (int t = 0; t < QB; ++t) qf[t] = QF[qbase + t * 64];

    const f32x16 zero = {0.f,0.f,0.f,0.f,0.f,0.f,0.f,0.f,
                         0.f,0.f,0.f,0.f,0.f,0.f,0.f,0.f};
    float mn[QB];
    #pragma unroll
    for (int t = 0; t < QB; ++t) mn[t] = 3.0e38f;

    const size_t tbase = ((size_t)bdT * TILES + ms * TPB) * 64 + lane;

    // Software-pipelined, MB=1: prefetch next tile while reducing current.
    f16x8 a = TA[tbase];
    for (int i = 0; i < ITER - 1; ++i) {
        f16x8 n = TA[tbase + (size_t)(i + 1) * 64];
        #pragma unroll
        for (int t = 0; t < QB; ++t) {
            f32x16 d = __builtin_amdgcn_mfma_f32_32x32x16_f16(a, qf[t], zero, 0, 0, 0);
            mn[t] = fminf(mn[t], red16(d));
        }
        a = n;
    }
    #pragma unroll
    for (int t = 0; t < QB; ++t) {
        f32x16 d = __builtin_amdgcn_mfma_f32_32x32x16_f16(a, qf[t], zero, 0, 0, 0);
        mn[t] = fminf(mn[t], red16(d));
    }

    // Each lane covered 16 of 32 rows per tile; other 16 rows are in lane^32.
    #pragma unroll
    for (int t = 0; t < QB; ++t) mn[t] = fminf(mn[t], __shfl_xor(mn[t], 32));

    if (lane < 32) {
        float* base = minarr + (size_t)ms * NQTOT + (size_t)bd * NPTS + qw * (QB * 32) + lane;
        #pragma unroll
        for (int t = 0; t < QB; ++t) base[t * 32] = mn[t];
    }
}

// ---- Reduce: min over MSPLIT partials, + |q|^2, sum, scale ----
__global__ __launch_bounds__(256) void chamfer_reduce(
    const float* __restrict__ minarr, const float* __restrict__ H,
    float* __restrict__ out)
{
    const int q = blockIdx.x * 256 + threadIdx.x;   // bd*8192 + n
    float m = 3.4e38f;
    #pragma unroll
    for (int ms = 0; ms < MSPLIT; ++ms)
        m = fminf(m, minarr[(size_t)ms * NQTOT + q]);
    float acc = m + H[q];
    #pragma unroll
    for (int off = 32; off > 0; off >>= 1) acc += __shfl_down(acc, off);

    __shared__ float sdata[4];
    if ((threadIdx.x & 63) == 0) sdata[threadIdx.x >> 6] = acc;
    __syncthreads();
    if (threadIdx.x == 0) {
        float t = (sdata[0] + sdata[1]) + (sdata[2] + sdata[3]);
        atomicAdd(out, t * (1.0f / (float)(BATCH * NPTS)));
    }
}

extern "C" void kernel_launch(void* const* d_in, const int* in_sizes, int n_in,
                              void* d_out, int out_size, void* d_ws, size_t ws_size,
                              hipStream_t stream) {
    const float* src = (const float*)d_in[0];   // (B, N, 3) fp32
    const float* tgt = (const float*)d_in[1];   // (B, M, 3) fp32
    float* out = (float*)d_out;

    f16x8* TA     = (f16x8*)((char*)d_ws + TA_OFF);
    f16x8* QF     = (f16x8*)((char*)d_ws + QF_OFF);
    float* H      = (float*)((char*)d_ws + H_OFF);
    float* minarr = (float*)((char*)d_ws + MIN_OFF);

    chamfer_prepack<<<NQTOT / 256, 256, 0, stream>>>(src, tgt, TA, QF, H, out);
    chamfer_main<<<64 * 8 * MSPLIT, 64, 0, stream>>>(TA, QF, minarr);
    chamfer_reduce<<<NQTOT / 256, 256, 0, stream>>>(minarr, H, out);
}

// Round 8
// 82.659 us; speedup vs baseline: 1.4347x; 1.0304x over previous
//
#include <hip/hip_runtime.h>

// Problem constants (B=4, N=M=8192, D=3)
#define NPTS   8192
#define BATCH  4
#define MSPLIT 16                // m-range splits per (b,dir)
#define QB     4                 // query tiles (32 queries each) per wave
#define TILES  (NPTS / 32)       // 256 point-tiles per (cloud,b)
#define TPB    (TILES / MSPLIT)  // 16 db tiles per wave
#define ITER   TPB               // one tile per inner iteration
#define NQTOT  (BATCH * 2 * NPTS)
#define NWAVES (64 * 8 * MSPLIT) // 8192 logical waves
#define WPB    4                 // waves per workgroup (beat the wg/CU cap)

typedef _Float16 f16x8  __attribute__((ext_vector_type(8)));
typedef float    f32x16 __attribute__((ext_vector_type(16)));

// ws layout (bytes):
//   TA  [8 bd][256 tile][64 lane] f16x8   @ 0        (2 MB)  db-role frags
//   QF  [8 bd][256 tile][64 lane] f16x8   @ 2 MB     (2 MB)  query-role frags
//   H   [8 bd][8192] fp32                 @ 4 MB     (256 KB) |p|^2 exact
//   MIN [MSPLIT][8 bd][8192] fp32         @ 4.25 MB  (4 MB)  partial mins
#define TA_OFF  0
#define QF_OFF  (2u << 20)
#define H_OFF   (4u << 20)
#define MIN_OFF ((4u << 20) + (256u << 10))

// ---- Prepack: per point build hi/lo f16 split K-vectors in MFMA lane order.
// A (db role)   k = [th.x th.y th.z  th.x th.y th.z  tl.x tl.y | tl.z tl.x tl.y tl.z  hth htl 0 0]
// B (query role)k = [rh.x rh.y rh.z  rl.x rl.y rl.z  rh.x rh.y | rh.z rl.x rl.y rl.z  1   1   0 0]
// (r = -2q). Dot = rh·th + rl·th + rh·tl + rl·tl + hth + htl ≈ ht - 2 q·t.
__global__ __launch_bounds__(256) void chamfer_prepack(
    const float* __restrict__ src, const float* __restrict__ tgt,
    f16x8* __restrict__ TA, f16x8* __restrict__ QF, float* __restrict__ H,
    float* __restrict__ out)
{
    int tid = blockIdx.x * 256 + threadIdx.x;      // (c*4+b)*8192 + pt
    if (tid == 0) out[0] = 0.0f;                   // replaces memset dispatch
    int c   = tid >> 15;
    int r   = tid & 32767;                         // b*8192 + pt
    const float* p = (c ? tgt : src) + (size_t)r * 3;
    float x = p[0], y = p[1], z = p[2];
    float h = x * x + y * y + z * z;
    H[tid] = h;

    _Float16 thx = (_Float16)x, thy = (_Float16)y, thz = (_Float16)z;
    _Float16 tlx = (_Float16)(x - (float)thx);
    _Float16 tly = (_Float16)(y - (float)thy);
    _Float16 tlz = (_Float16)(z - (float)thz);
    _Float16 hh  = (_Float16)h;
    _Float16 hl  = (_Float16)(h - (float)hh);

    float rx = -2.f * x, ry = -2.f * y, rz = -2.f * z;
    _Float16 rhx = (_Float16)rx, rhy = (_Float16)ry, rhz = (_Float16)rz;
    _Float16 rlx = (_Float16)(rx - (float)rhx);
    _Float16 rly = (_Float16)(ry - (float)rhy);
    _Float16 rlz = (_Float16)(rz - (float)rhz);

    int pt   = r & 8191;
    int bd   = tid >> 13;                          // c*4+b
    int tile = pt >> 5, ln = pt & 31;
    size_t base = ((size_t)bd * TILES + tile) * 64;

    _Float16 z0 = (_Float16)0.f, one = (_Float16)1.f;
    f16x8 alo = {thx, thy, thz, thx, thy, thz, tlx, tly};
    f16x8 ahi = {tlz, tlx, tly, tlz, hh,  hl,  z0,  z0 };
    TA[base + ln]      = alo;
    TA[base + 32 + ln] = ahi;
    f16x8 blo = {rhx, rhy, rhz, rlx, rly, rlz, rhx, rhy};
    f16x8 bhi = {rhz, rlx, rly, rlz, one, one, z0,  z0 };
    QF[base + ln]      = blo;
    QF[base + 32 + ln] = bhi;
}

// min3 tree over the 16 C regs (rows = 16 of 32 db points; other half in lane^32)
__device__ __forceinline__ float red16(const f32x16& d) {
    float a = fminf(fminf(d[0],  d[1]),  d[2]);
    float b = fminf(fminf(d[3],  d[4]),  d[5]);
    float c = fminf(fminf(d[6],  d[7]),  d[8]);
    float e = fminf(fminf(d[9],  d[10]), d[11]);
    float f = fminf(fminf(d[12], d[13]), d[14]);
    float g = fminf(fminf(a, b), d[15]);
    float h = fminf(fminf(c, e), f);
    return fminf(g, h);
}

// ---- Main: WPB=4 independent waves per 256-thread block (beats the
// workgroup-per-CU residency cap that single-wave blocks hit).
// grid = NWAVES/WPB = 2048 blocks -> 8 blocks/CU -> 32 waves/CU (8/SIMD).
__global__ __launch_bounds__(256, 8) void chamfer_main(
    const f16x8* __restrict__ TA, const f16x8* __restrict__ QF,
    float* __restrict__ minarr)
{
    const int wid  = blockIdx.x * WPB + (threadIdx.x >> 6);  // logical wave id
    const int lane = threadIdx.x & 63;
    const int qw   = wid & 63;
    const int bd   = (wid >> 6) & 7;     // dir*4+b (queries from cloud=dir)
    const int ms   = wid >> 9;           // 0..MSPLIT-1
    const int bdT  = bd ^ 4;             // db side = opposite cloud

    f16x8 qf[QB];
    size_t qbase = ((size_t)bd * TILES + qw * QB) * 64 + lane;
    #pragma unroll
    for (int t = 0; t < QB; ++t) qf[t] = QF[qbase + t * 64];

    const f32x16 zero = {0.f,0.f,0.f,0.f,0.f,0.f,0.f,0.f,
                         0.f,0.f,0.f,0.f,0.f,0.f,0.f,0.f};
    float mn[QB];
    #pragma unroll
    for (int t = 0; t < QB; ++t) mn[t] = 3.0e38f;

    const size_t tbase = ((size_t)bdT * TILES + ms * TPB) * 64 + lane;

    // Software-pipelined: prefetch next tile while reducing current.
    f16x8 a = TA[tbase];
    for (int i = 0; i < ITER - 1; ++i) {
        f16x8 n = TA[tbase + (size_t)(i + 1) * 64];
        #pragma unroll
        for (int t = 0; t < QB; ++t) {
            f32x16 d = __builtin_amdgcn_mfma_f32_32x32x16_f16(a, qf[t], zero, 0, 0, 0);
            mn[t] = fminf(mn[t], red16(d));
        }
        a = n;
    }
    #pragma unroll
    for (int t = 0; t < QB; ++t) {
        f32x16 d = __builtin_amdgcn_mfma_f32_32x32x16_f16(a, qf[t], zero, 0, 0, 0);
        mn[t] = fminf(mn[t], red16(d));
    }

    // Each lane covered 16 of 32 rows per tile; other 16 rows are in lane^32.
    #pragma unroll
    for (int t = 0; t < QB; ++t) mn[t] = fminf(mn[t], __shfl_xor(mn[t], 32));

    if (lane < 32) {
        float* base = minarr + (size_t)ms * NQTOT + (size_t)bd * NPTS + qw * (QB * 32) + lane;
        #pragma unroll
        for (int t = 0; t < QB; ++t) base[t * 32] = mn[t];
    }
}

// ---- Reduce: min over MSPLIT partials, + |q|^2, sum, scale ----
__global__ __launch_bounds__(256) void chamfer_reduce(
    const float* __restrict__ minarr, const float* __restrict__ H,
    float* __restrict__ out)
{
    const int q = blockIdx.x * 256 + threadIdx.x;   // bd*8192 + n
    float m = 3.4e38f;
    #pragma unroll
    for (int ms = 0; ms < MSPLIT; ++ms)
        m = fminf(m, minarr[(size_t)ms * NQTOT + q]);
    float acc = m + H[q];
    #pragma unroll
    for (int off = 32; off > 0; off >>= 1) acc += __shfl_down(acc, off);

    __shared__ float sdata[4];
    if ((threadIdx.x & 63) == 0) sdata[threadIdx.x >> 6] = acc;
    __syncthreads();
    if (threadIdx.x == 0) {
        float t = (sdata[0] + sdata[1]) + (sdata[2] + sdata[3]);
        atomicAdd(out, t * (1.0f / (float)(BATCH * NPTS)));
    }
}

extern "C" void kernel_launch(void* const* d_in, const int* in_sizes, int n_in,
                              void* d_out, int out_size, void* d_ws, size_t ws_size,
                              hipStream_t stream) {
    const float* src = (const float*)d_in[0];   // (B, N, 3) fp32
    const float* tgt = (const float*)d_in[1];   // (B, M, 3) fp32
    float* out = (float*)d_out;

    f16x8* TA     = (f16x8*)((char*)d_ws + TA_OFF);
    f16x8* QF     = (f16x8*)((char*)d_ws + QF_OFF);
    float* H      = (float*)((char*)d_ws + H_OFF);
    float* minarr = (float*)((char*)d_ws + MIN_OFF);

    chamfer_prepack<<<NQTOT / 256, 256, 0, stream>>>(src, tgt, TA, QF, H, out);
    chamfer_main<<<NWAVES / WPB, 256, 0, stream>>>(TA, QF, minarr);
    chamfer_reduce<<<NQTOT / 256, 256, 0, stream>>>(minarr, H, out);
}